// Round 4
// baseline (40.409 us; speedup 1.0000x reference)
//
#include <hip/hip_runtime.h>
#include <hip/hip_bf16.h>

#define B_SZ 4096
#define N_SZ 8192
#define D_SZ 128
#define CT 16                      // 32-col tiles per strip (512 cols)
#define NSTRIP (N_SZ / (CT * 32))  // 16 col strips

constexpr float TEMP = 0.5f;
constexpr float EPS = 1e-8f;
// exp(dot/TEMP) = exp2(dot * log2(e)/TEMP); sqrt of the scale folded into
// BOTH normalized vectors so the MFMA accumulator is directly the exp2 arg.
constexpr float SQS = 1.6986436006556212f;  // sqrt(log2(e)/TEMP)

typedef short short8 __attribute__((ext_vector_type(8)));
typedef float f32x16 __attribute__((ext_vector_type(16)));

// Tiled pn layout (bf16): byte addr of element (row r, col d) =
//   (r>>5)*8192 + (d>>3)*512 + (r&31)*16 + (d&7)*2
// -> each MFMA fragment chunk is 512B contiguous across 32 lanes; a whole
//    32-row tile is one contiguous 8KB block.

// ---------------------------------------------------------------------------
// Kernel A: per wave, handle row pair (r, r+B). Normalize into tiled-bf16 pn
// (scaled by SQS); exact-f32 positive-pair term -> posbuf[block];
// selfexp[r] = exp2(self-sim of the ROUNDED bf16 row) for later diag removal.
// ---------------------------------------------------------------------------
__global__ void norm_pos_kernel(const float* __restrict__ z_i,
                                const float* __restrict__ z_j,
                                unsigned int* __restrict__ pn_u32,
                                float* __restrict__ posbuf,
                                float* __restrict__ selfexp) {
    __shared__ float sp[4];
    int wid = threadIdx.x >> 6;
    int lane = threadIdx.x & 63;
    int r = blockIdx.x * 4 + wid;                 // [0, B)
    float2 vi = *reinterpret_cast<const float2*>(z_i + (size_t)r * D_SZ + lane * 2);
    float2 vj = *reinterpret_cast<const float2*>(z_j + (size_t)r * D_SZ + lane * 2);
    float ssi = vi.x * vi.x + vi.y * vi.y;
    float ssj = vj.x * vj.x + vj.y * vj.y;
    float dot = vi.x * vj.x + vi.y * vj.y;
#pragma unroll
    for (int m = 32; m >= 1; m >>= 1) {
        ssi += __shfl_xor(ssi, m, 64);
        ssj += __shfl_xor(ssj, m, 64);
        dot += __shfl_xor(dot, m, 64);
    }
    float ni = fmaxf(sqrtf(ssi), EPS);
    float nj = fmaxf(sqrtf(ssj), EPS);
    float si = SQS / ni, sj = SQS / nj;
    union { unsigned int u32; __hip_bfloat16 h[2]; } pki, pkj;
    pki.h[0] = __float2bfloat16(vi.x * si);
    pki.h[1] = __float2bfloat16(vi.y * si);
    pkj.h[0] = __float2bfloat16(vj.x * sj);
    pkj.h[1] = __float2bfloat16(vj.y * sj);
    // tiled store: lane l holds cols 2l, 2l+1 (one u32)
    int u = ((r >> 5) * 2048) + ((lane >> 2) * 128) + ((r & 31) * 4) + (lane & 3);
    pn_u32[u] = pki.u32;
    int r2 = r + B_SZ;
    int u2 = ((r2 >> 5) * 2048) + ((lane >> 2) * 128) + ((r2 & 31) * 4) + (lane & 3);
    pn_u32[u2] = pkj.u32;
    // self-similarity of the rounded rows (exp2 units, same scale as MFMA)
    float bx = __bfloat162float(pki.h[0]), by = __bfloat162float(pki.h[1]);
    float cx = __bfloat162float(pkj.h[0]), cy = __bfloat162float(pkj.h[1]);
    float sdi = bx * bx + by * by;
    float sdj = cx * cx + cy * cy;
#pragma unroll
    for (int m = 32; m >= 1; m >>= 1) {
        sdi += __shfl_xor(sdi, m, 64);
        sdj += __shfl_xor(sdj, m, 64);
    }
    if (lane == 0) {
        selfexp[r] = __builtin_amdgcn_exp2f(sdi);
        selfexp[r2] = __builtin_amdgcn_exp2f(sdj);
        sp[wid] = -dot / (ni * nj * TEMP) / (float)B_SZ;
    }
    __syncthreads();
    if (threadIdx.x == 0)
        posbuf[blockIdx.x] = sp[0] + sp[1] + sp[2] + sp[3];
}

// ---------------------------------------------------------------------------
// Kernel B: partial[strip][r] = sum over the strip's 512 cols of exp2(sim)
// (diagonal INCLUDED — removed later via selfexp). Block = 4 independent
// waves x 64 rows; no LDS, no barriers. B-panel streamed from L2 (pn = 2MB,
// fits per-XCD L2) with register double-buffering (static bA/bB names).
// C/D layout: col=lane&31, row=(reg&3)+8*(reg>>2)+4*(lane>>5).
// ---------------------------------------------------------------------------
__global__ __launch_bounds__(256, 2)
void simexp_kernel(const char* __restrict__ p, float* __restrict__ partial) {
    int wid = threadIdx.x >> 6;
    int lane = threadIdx.x & 63;
    int half = lane >> 5, lc = lane & 31;
    int rt0 = blockIdx.x * 8 + wid * 2;   // wave owns row-tiles rt0, rt0+1
    int ct0 = blockIdx.y * CT;

    // A fragments: coalesced 1KB loads, held for the whole kernel
    const char* afrag = p + (size_t)rt0 * 8192 + half * 512 + lc * 16;
    short8 a0[8], a1[8];
#pragma unroll
    for (int kc = 0; kc < 8; ++kc) {
        a0[kc] = *reinterpret_cast<const short8*>(afrag + kc * 1024);
        a1[kc] = *reinterpret_cast<const short8*>(afrag + 8192 + kc * 1024);
    }

    float rs0[16], rs1[16];
#pragma unroll
    for (int i = 0; i < 16; ++i) { rs0[i] = 0.0f; rs1[i] = 0.0f; }

    const char* bfrag = p + (size_t)ct0 * 8192 + half * 512 + lc * 16;
    short8 bA[8], bB[8];
#pragma unroll
    for (int kc = 0; kc < 8; ++kc)
        bA[kc] = *reinterpret_cast<const short8*>(bfrag + kc * 1024);

#pragma unroll 1
    for (int t = 0; t < CT; t += 2) {
        // ---- even tile t: compute with bA, prefetch tile t+1 into bB
        {
            const char* nb = bfrag + (size_t)(t + 1) * 8192;
#pragma unroll
            for (int kc = 0; kc < 8; ++kc)
                bB[kc] = *reinterpret_cast<const short8*>(nb + kc * 1024);
        }
        f32x16 acc0 = {}, acc1 = {};
#pragma unroll
        for (int kc = 0; kc < 8; ++kc) {
            acc0 = __builtin_amdgcn_mfma_f32_32x32x16_bf16(a0[kc], bA[kc], acc0, 0, 0, 0);
            acc1 = __builtin_amdgcn_mfma_f32_32x32x16_bf16(a1[kc], bA[kc], acc1, 0, 0, 0);
        }
#pragma unroll
        for (int r = 0; r < 16; ++r) {
            rs0[r] += __builtin_amdgcn_exp2f(acc0[r]);
            rs1[r] += __builtin_amdgcn_exp2f(acc1[r]);
        }
        // ---- odd tile t+1: compute with bB, prefetch tile t+2 into bA
        {
            int tn = (t + 2 < CT) ? (t + 2) : (CT - 1);  // clamp: redundant last load
            const char* nb = bfrag + (size_t)tn * 8192;
#pragma unroll
            for (int kc = 0; kc < 8; ++kc)
                bA[kc] = *reinterpret_cast<const short8*>(nb + kc * 1024);
        }
        f32x16 acc2 = {}, acc3 = {};
#pragma unroll
        for (int kc = 0; kc < 8; ++kc) {
            acc2 = __builtin_amdgcn_mfma_f32_32x32x16_bf16(a0[kc], bB[kc], acc2, 0, 0, 0);
            acc3 = __builtin_amdgcn_mfma_f32_32x32x16_bf16(a1[kc], bB[kc], acc3, 0, 0, 0);
        }
#pragma unroll
        for (int r = 0; r < 16; ++r) {
            rs0[r] += __builtin_amdgcn_exp2f(acc2[r]);
            rs1[r] += __builtin_amdgcn_exp2f(acc3[r]);
        }
    }

    // reduce across the 32 column lanes
#pragma unroll
    for (int m = 1; m <= 16; m <<= 1) {
#pragma unroll
        for (int r = 0; r < 16; ++r) {
            rs0[r] += __shfl_xor(rs0[r], m, 64);
            rs1[r] += __shfl_xor(rs1[r], m, 64);
        }
    }
    if (lc == 0) {
        float* dst = partial + (size_t)blockIdx.y * N_SZ;
#pragma unroll
        for (int r = 0; r < 16; ++r) {
            int lrow = (r & 3) + 8 * (r >> 2) + 4 * half;
            dst[rt0 * 32 + lrow] = rs0[r];
            dst[(rt0 + 1) * 32 + lrow] = rs1[r];
        }
    }
}

// ---------------------------------------------------------------------------
// Kernel C: loss = sum(log(rowsum - selfexp))/2B + pos partials. 32 x 256.
// ---------------------------------------------------------------------------
__global__ void lse_kernel(const float* __restrict__ partial,
                           const float* __restrict__ selfexp,
                           const float* __restrict__ posbuf,
                           float* __restrict__ out) {
    __shared__ float sred[4];
    int r = blockIdx.x * 256 + threadIdx.x;
    float s = 0.0f;
#pragma unroll
    for (int c = 0; c < NSTRIP; ++c) s += partial[(size_t)c * N_SZ + r];
    s -= selfexp[r];
    float v = __logf(s) * (1.0f / (float)N_SZ);
    if (threadIdx.x < 32) v += posbuf[blockIdx.x * 32 + threadIdx.x];
#pragma unroll
    for (int m = 32; m >= 1; m >>= 1) v += __shfl_xor(v, m, 64);
    int wid = threadIdx.x >> 6;
    if ((threadIdx.x & 63) == 0) sred[wid] = v;
    __syncthreads();
    if (threadIdx.x == 0)
        atomicAdd(out, sred[0] + sred[1] + sred[2] + sred[3]);
}

// ---------------------------------------------------------------------------
extern "C" void kernel_launch(void* const* d_in, const int* in_sizes, int n_in,
                              void* d_out, int out_size, void* d_ws, size_t ws_size,
                              hipStream_t stream) {
    const float* z_i = (const float*)d_in[0];
    const float* z_j = (const float*)d_in[1];
    float* out = (float*)d_out;
    char* ws = (char*)d_ws;

    unsigned int* pn = (unsigned int*)ws;                            // 2 MiB
    float* partial = (float*)(ws + (size_t)N_SZ * D_SZ * 2);         // 512 KiB
    float* selfexp = partial + (size_t)NSTRIP * N_SZ;                // 32 KiB
    float* posbuf = selfexp + N_SZ;                                  // 4 KiB

    hipMemsetAsync(out, 0, sizeof(float), stream);

    norm_pos_kernel<<<B_SZ / 4, 256, 0, stream>>>(z_i, z_j, pn, posbuf, selfexp);

    dim3 grid(N_SZ / 256, NSTRIP);  // 32 x 16
    simexp_kernel<<<grid, 256, 0, stream>>>((const char*)pn, partial);

    lse_kernel<<<N_SZ / 256, 256, 0, stream>>>(partial, selfexp, posbuf, out);
}

// Round 5
// 37.958 us; speedup vs baseline: 1.0646x; 1.0646x over previous
//
#include <hip/hip_runtime.h>
#include <hip/hip_bf16.h>

#define B_SZ 4096
#define N_SZ 8192
#define D_SZ 128
#define CT 16                      // 32-col tiles per strip (512 cols)
#define NSTRIP (N_SZ / (CT * 32))  // 16 col strips

constexpr float TEMP = 0.5f;
constexpr float EPS = 1e-8f;
// exp(dot/TEMP) = exp2(dot * log2(e)/TEMP); sqrt of the scale folded into
// BOTH normalized vectors so the MFMA accumulator is directly the exp2 arg.
constexpr float SQS = 1.6986436006556212f;  // sqrt(log2(e)/TEMP)

typedef short short8 __attribute__((ext_vector_type(8)));
typedef float f32x16 __attribute__((ext_vector_type(16)));

// Tiled pn layout (bf16): byte addr of element (row r, col d) =
//   (r>>5)*8192 + (d>>3)*512 + (r&31)*16 + (d&7)*2
// -> each MFMA fragment chunk is 512B contiguous across 32 lanes; a whole
//    32-row tile is one contiguous 8KB block.

// ---------------------------------------------------------------------------
// Kernel A: per wave, handle row pair (r, r+B). Normalize into tiled-bf16 pn
// (scaled by SQS); exact-f32 positive-pair term -> posbuf[block];
// selfexp[r] = exp2(self-sim of the ROUNDED bf16 row) for later diag removal.
// ---------------------------------------------------------------------------
__global__ void norm_pos_kernel(const float* __restrict__ z_i,
                                const float* __restrict__ z_j,
                                unsigned int* __restrict__ pn_u32,
                                float* __restrict__ posbuf,
                                float* __restrict__ selfexp) {
    __shared__ float sp[4];
    int wid = threadIdx.x >> 6;
    int lane = threadIdx.x & 63;
    int r = blockIdx.x * 4 + wid;                 // [0, B)
    float2 vi = *reinterpret_cast<const float2*>(z_i + (size_t)r * D_SZ + lane * 2);
    float2 vj = *reinterpret_cast<const float2*>(z_j + (size_t)r * D_SZ + lane * 2);
    float ssi = vi.x * vi.x + vi.y * vi.y;
    float ssj = vj.x * vj.x + vj.y * vj.y;
    float dot = vi.x * vj.x + vi.y * vj.y;
#pragma unroll
    for (int m = 32; m >= 1; m >>= 1) {
        ssi += __shfl_xor(ssi, m, 64);
        ssj += __shfl_xor(ssj, m, 64);
        dot += __shfl_xor(dot, m, 64);
    }
    float ni = fmaxf(sqrtf(ssi), EPS);
    float nj = fmaxf(sqrtf(ssj), EPS);
    float si = SQS / ni, sj = SQS / nj;
    union { unsigned int u32; __hip_bfloat16 h[2]; } pki, pkj;
    pki.h[0] = __float2bfloat16(vi.x * si);
    pki.h[1] = __float2bfloat16(vi.y * si);
    pkj.h[0] = __float2bfloat16(vj.x * sj);
    pkj.h[1] = __float2bfloat16(vj.y * sj);
    // tiled store: lane l holds cols 2l, 2l+1 (one u32)
    int u = ((r >> 5) * 2048) + ((lane >> 2) * 128) + ((r & 31) * 4) + (lane & 3);
    pn_u32[u] = pki.u32;
    int r2 = r + B_SZ;
    int u2 = ((r2 >> 5) * 2048) + ((lane >> 2) * 128) + ((r2 & 31) * 4) + (lane & 3);
    pn_u32[u2] = pkj.u32;
    // self-similarity of the rounded rows (exp2 units, same scale as MFMA)
    float bx = __bfloat162float(pki.h[0]), by = __bfloat162float(pki.h[1]);
    float cx = __bfloat162float(pkj.h[0]), cy = __bfloat162float(pkj.h[1]);
    float sdi = bx * bx + by * by;
    float sdj = cx * cx + cy * cy;
#pragma unroll
    for (int m = 32; m >= 1; m >>= 1) {
        sdi += __shfl_xor(sdi, m, 64);
        sdj += __shfl_xor(sdj, m, 64);
    }
    if (lane == 0) {
        selfexp[r] = __builtin_amdgcn_exp2f(sdi);
        selfexp[r2] = __builtin_amdgcn_exp2f(sdj);
        sp[wid] = -dot / (ni * nj * TEMP) / (float)B_SZ;
    }
    __syncthreads();
    if (threadIdx.x == 0)
        posbuf[blockIdx.x] = sp[0] + sp[1] + sp[2] + sp[3];
}

// ---------------------------------------------------------------------------
// Kernel B: partial[strip][r] = sum over the strip's 512 cols of exp2(sim)
// (diagonal INCLUDED — removed later via selfexp).
// Block = 4 waves x 1 row-tile each (128 rows); col strip = 16 tiles;
// B-tile (8KB contiguous) double-buffered in LDS via global_load_lds.
// Occupancy-first: VGPR <= 128 -> 4 waves/SIMD (16 waves/CU, 4 blocks/CU);
// K-split dual MFMA chains halve dep depth.
// C/D layout: col=lane&31, row=(reg&3)+8*(reg>>2)+4*(lane>>5).
// ---------------------------------------------------------------------------
__global__ __launch_bounds__(256, 4)
void simexp_kernel(const char* __restrict__ p, float* __restrict__ partial) {
    __shared__ char smem[2][8192];
    int wid = threadIdx.x >> 6;
    int lane = threadIdx.x & 63;
    int half = lane >> 5, lc = lane & 31;
    int rt = blockIdx.x * 4 + wid;     // wave owns row-tile rt (32 rows)
    int ct0 = blockIdx.y * CT;

    // A fragments: coalesced 1KB loads, held for the whole kernel
    const char* afrag = p + (size_t)rt * 8192 + half * 512 + lc * 16;
    short8 a[8];
#pragma unroll
    for (int kc = 0; kc < 8; ++kc)
        a[kc] = *reinterpret_cast<const short8*>(afrag + kc * 1024);

    float rs[16];
#pragma unroll
    for (int i = 0; i < 16; ++i) rs[i] = 0.0f;

    // stage one 8KB col-tile: 2 global_load_lds per wave (linear copy)
    auto stage = [&](int buf, int ct) {
#pragma unroll
        for (int i = 0; i < 2; ++i) {
            int seg = i * 4 + wid;
            const char* g = p + (size_t)ct * 8192 + seg * 1024 + lane * 16;
            __builtin_amdgcn_global_load_lds(
                (const __attribute__((address_space(1))) unsigned int*)g,
                (__attribute__((address_space(3))) unsigned int*)&smem[buf][seg * 1024],
                16, 0, 0);
        }
    };

    stage(0, ct0);
    __syncthreads();

#pragma unroll 1
    for (int t = 0; t < CT; ++t) {
        if (t + 1 < CT) stage((t + 1) & 1, ct0 + t + 1);
        const char* bb = &smem[t & 1][0] + half * 512 + lc * 16;
        short8 b[8];
#pragma unroll
        for (int kc = 0; kc < 8; ++kc)
            b[kc] = *reinterpret_cast<const short8*>(bb + kc * 1024);
        // K-split dual chains: dep depth 4 instead of 8
        f32x16 accL = {}, accH = {};
#pragma unroll
        for (int kc = 0; kc < 4; ++kc) {
            accL = __builtin_amdgcn_mfma_f32_32x32x16_bf16(a[kc], b[kc], accL, 0, 0, 0);
            accH = __builtin_amdgcn_mfma_f32_32x32x16_bf16(a[kc + 4], b[kc + 4], accH, 0, 0, 0);
        }
#pragma unroll
        for (int r = 0; r < 16; ++r)
            rs[r] += __builtin_amdgcn_exp2f(accL[r] + accH[r]);
        __syncthreads();
    }

    // reduce across the 32 column lanes
#pragma unroll
    for (int m = 1; m <= 16; m <<= 1) {
#pragma unroll
        for (int r = 0; r < 16; ++r)
            rs[r] += __shfl_xor(rs[r], m, 64);
    }
    if (lc == 0) {
        float* dst = partial + (size_t)blockIdx.y * N_SZ;
#pragma unroll
        for (int r = 0; r < 16; ++r) {
            int lrow = (r & 3) + 8 * (r >> 2) + 4 * half;
            dst[rt * 32 + lrow] = rs[r];
        }
    }
}

// ---------------------------------------------------------------------------
// Kernel C: loss = sum(log(rowsum - selfexp))/2B + pos partials. 32 x 256.
// ---------------------------------------------------------------------------
__global__ void lse_kernel(const float* __restrict__ partial,
                           const float* __restrict__ selfexp,
                           const float* __restrict__ posbuf,
                           float* __restrict__ out) {
    __shared__ float sred[4];
    int r = blockIdx.x * 256 + threadIdx.x;
    float s = 0.0f;
#pragma unroll
    for (int c = 0; c < NSTRIP; ++c) s += partial[(size_t)c * N_SZ + r];
    s -= selfexp[r];
    float v = __logf(s) * (1.0f / (float)N_SZ);
    if (threadIdx.x < 32) v += posbuf[blockIdx.x * 32 + threadIdx.x];
#pragma unroll
    for (int m = 32; m >= 1; m >>= 1) v += __shfl_xor(v, m, 64);
    int wid = threadIdx.x >> 6;
    if ((threadIdx.x & 63) == 0) sred[wid] = v;
    __syncthreads();
    if (threadIdx.x == 0)
        atomicAdd(out, sred[0] + sred[1] + sred[2] + sred[3]);
}

// ---------------------------------------------------------------------------
extern "C" void kernel_launch(void* const* d_in, const int* in_sizes, int n_in,
                              void* d_out, int out_size, void* d_ws, size_t ws_size,
                              hipStream_t stream) {
    const float* z_i = (const float*)d_in[0];
    const float* z_j = (const float*)d_in[1];
    float* out = (float*)d_out;
    char* ws = (char*)d_ws;

    unsigned int* pn = (unsigned int*)ws;                            // 2 MiB
    float* partial = (float*)(ws + (size_t)N_SZ * D_SZ * 2);         // 512 KiB
    float* selfexp = partial + (size_t)NSTRIP * N_SZ;                // 32 KiB
    float* posbuf = selfexp + N_SZ;                                  // 4 KiB

    hipMemsetAsync(out, 0, sizeof(float), stream);

    norm_pos_kernel<<<B_SZ / 4, 256, 0, stream>>>(z_i, z_j, pn, posbuf, selfexp);

    dim3 grid(N_SZ / 128, NSTRIP);  // 64 x 16 = 1024 blocks
    simexp_kernel<<<grid, 256, 0, stream>>>((const char*)pn, partial);

    lse_kernel<<<N_SZ / 256, 256, 0, stream>>>(partial, selfexp, posbuf, out);
}